// Round 11
// baseline (334.783 us; speedup 1.0000x reference)
//
#include <hip/hip_runtime.h>
#include <math.h>
#include <stdint.h>

#define M_ROWS 8192
#define N_COLS 16384
#define K_DIM  256
#define NTILE  (N_COLS / 128)   // 128 col tiles
#define CHUNK  2048             // fallback path only
#define NCHUNK 4

typedef _Float16 half8  __attribute__((ext_vector_type(8)));
typedef _Float16 half4v __attribute__((ext_vector_type(4)));
typedef float    vf4    __attribute__((ext_vector_type(4)));

__device__ __forceinline__ void gload16(const void* g, void* lds) {
  // async global->LDS, 16B per lane; LDS dest = wave-uniform base + lane*16
  __builtin_amdgcn_global_load_lds(
      (__attribute__((address_space(1))) void*)(void*)g,
      (__attribute__((address_space(3))) void*)lds, 16, 0, 0);
}

// ---------------- prep: fp16 copies + exact f32 norms -----------------
__global__ __launch_bounds__(256) void prep_kernel(
    const float* __restrict__ x, const float* __restrict__ w,
    float* __restrict__ x2, float* __restrict__ w2,
    _Float16* __restrict__ xh, _Float16* __restrict__ wh) {
  int row  = blockIdx.x * 4 + (threadIdx.x >> 6);  // one wave per row
  int lane = threadIdx.x & 63;
  const float* src; _Float16* dst; float* nrm;
  if (row < M_ROWS) {
    src = x + (size_t)row * K_DIM; dst = xh + (size_t)row * K_DIM; nrm = x2 + row;
  } else {
    int r = row - M_ROWS;
    src = w + (size_t)r * K_DIM; dst = wh + (size_t)r * K_DIM; nrm = w2 + r;
  }
  float4 v = ((const float4*)src)[lane];           // 64 lanes x 4 = 256
  float s = v.x*v.x + v.y*v.y + v.z*v.z + v.w*v.w;
  #pragma unroll
  for (int off = 32; off > 0; off >>= 1) s += __shfl_down(s, off);
  if (lane == 0) *nrm = s;
  half4v h; h[0]=(_Float16)v.x; h[1]=(_Float16)v.y; h[2]=(_Float16)v.z; h[3]=(_Float16)v.w;
  ((half4v*)dst)[lane] = h;
}

// -------- 128x128xBK64 GEMM, R10 base (512 thr / 8 waves 2x4, 16 waves/CU,
// T2 swizzle per rule #21) + PEELED LAST K-TILE: per row-group m, final
// MFMAs are immediately followed by that group's exp+stores, so store
// issue overlaps remaining MFMA tail. MODE 1 drops the trailing barrier
// (epilogue reads only registers + prologue LDS) to desync waves into
// the write phase.
// MODE 0: per-row exp-sum partials.  MODE 1: write normalized softmax.
template <int MODE>
__global__ __launch_bounds__(512, 4) void gemm_pass(
    const _Float16* __restrict__ A, const _Float16* __restrict__ Bm,
    const float* __restrict__ x2g, const float* __restrict__ w2g,
    const float* __restrict__ invg,
    float* __restrict__ partials,
    float* __restrict__ out) {
  __shared__ _Float16 As[128 * 64];   // 16KB, swizzled contents
  __shared__ _Float16 Bs[128 * 64];   // 16KB
  __shared__ float x2s[128];
  __shared__ float w2s[128];
  __shared__ float invs[128];
  __shared__ float rowpart[4][128];   // per-wc partial row sums (MODE 0)

  // XCD partition: xcd = id&7 owns 16 contiguous col-tiles (w slice 1MB, L2-resident);
  // within an XCD, col-tile varies fastest -> A-tile reused 16x consecutively.
  int id   = blockIdx.x;            // grid = 64 row-tiles * 128 col-tiles = 8192
  int xcd  = id & 7;
  int rest = id >> 3;               // 0..1023
  int ct   = xcd * 16 + (rest & 15);
  int rt   = rest >> 4;             // 0..63
  int brow = rt * 128;
  int bcol = ct * 128;

  int tid = threadIdx.x, lane = tid & 63, wid = tid >> 6;
  int wr = wid >> 2, wc = wid & 3;  // 2x4 waves, each 64x32 output

  if (tid < 128) {
    x2s[tid] = x2g[brow + tid];
    if (MODE == 1) invs[tid] = invg[brow + tid];
  } else if (tid < 256) {
    w2s[tid - 128] = w2g[bcol + tid - 128];
  }

  vf4 acc[4][2] = {};

  // stage K-tile at offset kk into LDS (2 segs/wave/matrix).
  // LDS dest linear; global source column pre-swizzled (involution):
  // LDS[row][cb] = global[row][cb ^ ((row&7)<<4)].
  auto stage = [&](int kk) {
    #pragma unroll
    for (int i = 0; i < 2; ++i) {
      int seg = wid * 2 + i;
      int r   = seg * 8 + (lane >> 3);
      int colhalf = ((lane & 7) * 8) ^ ((lane >> 3) << 3);   // fp16 elems
      gload16(A  + (size_t)(brow + r) * K_DIM + kk + colhalf, (char*)As + seg * 1024);
      gload16(Bm + (size_t)(bcol + r) * K_DIM + kk + colhalf, (char*)Bs + seg * 1024);
    }
  };

  // ---- main K-tiles 0..2 (kk = 0,64,128): verified R6/R10 schedule ----
  for (int kk = 0; kk < K_DIM - 64; kk += 64) {
    stage(kk);
    __syncthreads();   // compiler drains vmcnt(0) before s_barrier
    #pragma unroll
    for (int ks = 0; ks < 2; ++ks) {          // two K=32 MFMA steps per BK=64
      half8 af[4], bf[2];
      int cb = ks * 64 + (lane >> 4) * 16;    // column byte within 128B row
      #pragma unroll
      for (int m = 0; m < 4; ++m) {
        int ra = wr * 64 + m * 16 + (lane & 15);
        af[m] = *(const half8*)((const char*)As + ra * 128 + (cb ^ ((ra & 7) << 4)));
      }
      #pragma unroll
      for (int n = 0; n < 2; ++n) {
        int rb = wc * 32 + n * 16 + (lane & 15);
        bf[n] = *(const half8*)((const char*)Bs + rb * 128 + (cb ^ ((rb & 7) << 4)));
      }
      #pragma unroll
      for (int m = 0; m < 4; ++m)
        #pragma unroll
        for (int n = 0; n < 2; ++n)
          acc[m][n] = __builtin_amdgcn_mfma_f32_16x16x32_f16(af[m], bf[n], acc[m][n], 0, 0, 0);
    }
    __syncthreads();
  }

  // ---- peeled last K-tile (kk = 192): fuse epilogue per row-group m ----
  stage(K_DIM - 64);
  __syncthreads();

  // B fragments for both ks, loaded once (4 x half8 = 16 VGPR)
  half8 bf2[2][2];
  #pragma unroll
  for (int ks = 0; ks < 2; ++ks) {
    int cb = ks * 64 + (lane >> 4) * 16;
    #pragma unroll
    for (int n = 0; n < 2; ++n) {
      int rb = wc * 32 + n * 16 + (lane & 15);
      bf2[ks][n] = *(const half8*)((const char*)Bs + rb * 128 + (cb ^ ((rb & 7) << 4)));
    }
  }

  #pragma unroll
  for (int m = 0; m < 4; ++m) {
    // final MFMAs for row-group m
    int ra = wr * 64 + m * 16 + (lane & 15);
    #pragma unroll
    for (int ks = 0; ks < 2; ++ks) {
      int cb = ks * 64 + (lane >> 4) * 16;
      half8 af = *(const half8*)((const char*)As + ra * 128 + (cb ^ ((ra & 7) << 4)));
      #pragma unroll
      for (int n = 0; n < 2; ++n)
        acc[m][n] = __builtin_amdgcn_mfma_f32_16x16x32_f16(af, bf2[ks][n], acc[m][n], 0, 0, 0);
    }
    // immediate epilogue for row-group m: stores issue while m+1.. MFMAs run
    if (MODE == 0) {
      #pragma unroll
      for (int j = 0; j < 4; ++j) {
        int rl = wr * 64 + m * 16 + ((lane >> 4) << 2) + j;   // C/D: row=(lane>>4)*4+j
        float x2v = x2s[rl];
        float sm = 0.f;
        #pragma unroll
        for (int n = 0; n < 2; ++n) {
          int cl = wc * 32 + n * 16 + (lane & 15);            // C/D: col=lane&15
          float d2 = fmaxf(x2v + w2s[cl] - 2.0f * acc[m][n][j], 0.0f);
          sm += __expf(-2.0f * sqrtf(d2));
        }
        sm += __shfl_xor(sm, 1);
        sm += __shfl_xor(sm, 2);
        sm += __shfl_xor(sm, 4);
        sm += __shfl_xor(sm, 8);
        if ((lane & 15) == 0) rowpart[wc][rl] = sm;   // rl disjoint across wr
      }
    } else {
      #pragma unroll
      for (int j = 0; j < 4; ++j) {
        int rl = wr * 64 + m * 16 + ((lane >> 4) << 2) + j;
        float x2v = x2s[rl];
        float inv = invs[rl];
        size_t rowbase = (size_t)(brow + rl) * N_COLS + bcol;
        #pragma unroll
        for (int n = 0; n < 2; ++n) {
          int cl = wc * 32 + n * 16 + (lane & 15);
          float d2 = fmaxf(x2v + w2s[cl] - 2.0f * acc[m][n][j], 0.0f);
          out[rowbase + cl] = __expf(-2.0f * sqrtf(d2)) * inv;
        }
      }
    }
  }

  if (MODE == 0) {
    __syncthreads();   // all rowpart written
    if (tid < 128)
      partials[(size_t)(brow + tid) * NTILE + ct] =
          rowpart[0][tid] + rowpart[1][tid] + rowpart[2][tid] + rowpart[3][tid];
  }
  // MODE 1: no trailing barrier — waves retire into the write phase desynced
}

// ------------- reduce partials -> 1/rowsum, one wave per row -----------
__global__ __launch_bounds__(256) void reduce_inv(
    const float* __restrict__ partials, float* __restrict__ invg) {
  int row  = blockIdx.x * 4 + (threadIdx.x >> 6);
  int lane = threadIdx.x & 63;
  const float* p = partials + (size_t)row * NTILE;
  float s = p[lane] + p[lane + 64];   // NTILE == 128
  #pragma unroll
  for (int off = 32; off > 0; off >>= 1) s += __shfl_down(s, off);
  if (lane == 0) invg[row] = 1.0f / s;
}

// =============== fallback path (ws tiny): logits + row softmax ===============
__global__ __launch_bounds__(256, 2) void gemm_logit_f32(
    const float* __restrict__ xf, const float* __restrict__ wf,
    float* __restrict__ out, int mbase) {
  __shared__ _Float16 As[128 * 64];
  __shared__ _Float16 Bs[128 * 64];
  __shared__ float x2s[128];
  __shared__ float w2s[128];

  int id  = blockIdx.x;
  int xcd = id & 7;
  int rt  = (id >> 3) & 15;
  int c2  = id >> 7;
  int brow = mbase + rt * 128;
  int bcol = (xcd * 16 + c2) * 128;

  int tid = threadIdx.x, lane = tid & 63, wid = tid >> 6;
  int wr = wid >> 1, wc = wid & 1;

  vf4 acc[4][4] = {};

  {
    const float* src = (tid < 128) ? xf + (size_t)(brow + tid) * K_DIM
                                   : wf + (size_t)(bcol + tid - 128) * K_DIM;
    float s = 0.f;
    for (int i = 0; i < 64; ++i) {
      float4 v = ((const float4*)src)[i];
      s += v.x*v.x + v.y*v.y + v.z*v.z + v.w*v.w;
    }
    if (tid < 128) x2s[tid] = s; else w2s[tid - 128] = s;
  }

  for (int kk = 0; kk < K_DIM; kk += 64) {
    #pragma unroll
    for (int i = 0; i < 8; ++i) {
      int idx = i * 256 + tid;
      int r = idx >> 4, kq = idx & 15;
      float4 va = ((const float4*)(xf + (size_t)(brow + r) * K_DIM + kk))[kq];
      float4 vb = ((const float4*)(wf + (size_t)(bcol + r) * K_DIM + kk))[kq];
      half4v ha; ha[0]=(_Float16)va.x; ha[1]=(_Float16)va.y; ha[2]=(_Float16)va.z; ha[3]=(_Float16)va.w;
      half4v hb; hb[0]=(_Float16)vb.x; hb[1]=(_Float16)vb.y; hb[2]=(_Float16)vb.z; hb[3]=(_Float16)vb.w;
      *(half4v*)&As[r * 64 + kq * 4] = ha;
      *(half4v*)&Bs[r * 64 + kq * 4] = hb;
    }
    __syncthreads();
    #pragma unroll
    for (int ks = 0; ks < 2; ++ks) {
      half8 af[4], bf[4];
      #pragma unroll
      for (int m = 0; m < 4; ++m)
        af[m] = *(const half8*)&As[(wr*64 + m*16 + (lane & 15)) * 64 + ks*32 + (lane >> 4) * 8];
      #pragma unroll
      for (int n = 0; n < 4; ++n)
        bf[n] = *(const half8*)&Bs[(wc*64 + n*16 + (lane & 15)) * 64 + ks*32 + (lane >> 4) * 8];
      #pragma unroll
      for (int m = 0; m < 4; ++m)
        #pragma unroll
        for (int n = 0; n < 4; ++n)
          acc[m][n] = __builtin_amdgcn_mfma_f32_16x16x32_f16(af[m], bf[n], acc[m][n], 0, 0, 0);
    }
    __syncthreads();
  }

  #pragma unroll
  for (int m = 0; m < 4; ++m) {
    int rl = wr * 64 + m * 16 + ((lane >> 4) << 2);
    #pragma unroll
    for (int n = 0; n < 4; ++n) {
      int cl = wc * 64 + n * 16 + (lane & 15);
      int c  = bcol + cl;
      float w2v = w2s[cl];
      #pragma unroll
      for (int j = 0; j < 4; ++j) {
        int r = brow + rl + j;
        float d2 = fmaxf(x2s[rl + j] + w2v - 2.0f * acc[m][n][j], 0.0f);
        out[(size_t)r * N_COLS + c] = -2.0f * sqrtf(d2);
      }
    }
  }
}

__global__ __launch_bounds__(256) void softmax_norm(float* __restrict__ io, int mbase) {
  int row = mbase + blockIdx.x;
  float* p = io + (size_t)row * N_COLS;
  int tid = threadIdx.x;
  __shared__ float wsum[4];

  float4 v[16];
  float s = 0.f;
  #pragma unroll
  for (int i = 0; i < 16; ++i) {
    v[i] = ((const float4*)p)[i * 256 + tid];
    v[i].x = __expf(v[i].x); v[i].y = __expf(v[i].y);
    v[i].z = __expf(v[i].z); v[i].w = __expf(v[i].w);
    s += v[i].x + v[i].y + v[i].z + v[i].w;
  }
  #pragma unroll
  for (int off = 32; off > 0; off >>= 1) s += __shfl_down(s, off);
  if ((tid & 63) == 0) wsum[tid >> 6] = s;
  __syncthreads();
  float inv = 1.0f / (wsum[0] + wsum[1] + wsum[2] + wsum[3]);
  #pragma unroll
  for (int i = 0; i < 16; ++i) {
    float4 o = v[i];
    o.x *= inv; o.y *= inv; o.z *= inv; o.w *= inv;
    ((float4*)p)[i * 256 + tid] = o;
  }
}

extern "C" void kernel_launch(void* const* d_in, const int* in_sizes, int n_in,
                              void* d_out, int out_size, void* d_ws, size_t ws_size,
                              hipStream_t stream) {
  const float* x = (const float*)d_in[0];
  const float* w = (const float*)d_in[1];
  float* out = (float*)d_out;

  // ws layout: x2[8192] | w2[16384] | invsum[8192] | partials[8192*128] |
  //            xh fp16 [8192*256] | wh fp16 [16384*256]
  char* ws = (char*)d_ws;
  float* x2 = (float*)ws;
  float* w2 = x2 + M_ROWS;
  float* invsum = w2 + N_COLS;
  float* partials = invsum + M_ROWS;
  _Float16* xh = (_Float16*)(partials + (size_t)M_ROWS * NTILE);
  _Float16* wh = xh + (size_t)M_ROWS * K_DIM;
  const size_t need = ((size_t)(M_ROWS + N_COLS + M_ROWS) + (size_t)M_ROWS * NTILE) * 4
                    + (size_t)(M_ROWS + N_COLS) * K_DIM * 2;

  if (ws_size >= need) {
    prep_kernel<<<(M_ROWS + N_COLS) / 4, 256, 0, stream>>>(x, w, x2, w2, xh, wh);
    gemm_pass<0><<<(M_ROWS / 128) * (N_COLS / 128), 512, 0, stream>>>(
        xh, wh, x2, w2, nullptr, partials, nullptr);
    reduce_inv<<<M_ROWS / 4, 256, 0, stream>>>(partials, invsum);
    gemm_pass<1><<<(M_ROWS / 128) * (N_COLS / 128), 512, 0, stream>>>(
        xh, wh, x2, w2, invsum, nullptr, out);
  } else {
    for (int c = 0; c < NCHUNK; ++c) {
      int mbase = c * CHUNK;
      gemm_logit_f32<<<(CHUNK / 128) * (N_COLS / 128), 256, 0, stream>>>(
          x, w, out, mbase);
      softmax_norm<<<CHUNK, 256, 0, stream>>>(out, mbase);
    }
  }
}

// Round 12
// 310.411 us; speedup vs baseline: 1.0785x; 1.0785x over previous
//
#include <hip/hip_runtime.h>
#include <math.h>
#include <stdint.h>

#define M_ROWS 8192
#define N_COLS 16384
#define K_DIM  256
#define NTILE  (N_COLS / 128)   // 128 col tiles
#define CHUNK  2048             // fallback path only
#define NCHUNK 4

typedef _Float16 half8  __attribute__((ext_vector_type(8)));
typedef _Float16 half4v __attribute__((ext_vector_type(4)));
typedef float    vf4    __attribute__((ext_vector_type(4)));

__device__ __forceinline__ void gload16(const void* g, void* lds) {
  // async global->LDS, 16B per lane; LDS dest = wave-uniform base + lane*16
  __builtin_amdgcn_global_load_lds(
      (__attribute__((address_space(1))) void*)(void*)g,
      (__attribute__((address_space(3))) void*)lds, 16, 0, 0);
}

// ---------------- prep: fp16 copies + exact f32 norms -----------------
__global__ __launch_bounds__(256) void prep_kernel(
    const float* __restrict__ x, const float* __restrict__ w,
    float* __restrict__ x2, float* __restrict__ w2,
    _Float16* __restrict__ xh, _Float16* __restrict__ wh) {
  int row  = blockIdx.x * 4 + (threadIdx.x >> 6);  // one wave per row
  int lane = threadIdx.x & 63;
  const float* src; _Float16* dst; float* nrm;
  if (row < M_ROWS) {
    src = x + (size_t)row * K_DIM; dst = xh + (size_t)row * K_DIM; nrm = x2 + row;
  } else {
    int r = row - M_ROWS;
    src = w + (size_t)r * K_DIM; dst = wh + (size_t)r * K_DIM; nrm = w2 + r;
  }
  float4 v = ((const float4*)src)[lane];           // 64 lanes x 4 = 256
  float s = v.x*v.x + v.y*v.y + v.z*v.z + v.w*v.w;
  #pragma unroll
  for (int off = 32; off > 0; off >>= 1) s += __shfl_down(s, off);
  if (lane == 0) *nrm = s;
  half4v h; h[0]=(_Float16)v.x; h[1]=(_Float16)v.y; h[2]=(_Float16)v.z; h[3]=(_Float16)v.w;
  ((half4v*)dst)[lane] = h;
}

// -------- 128x128xBK64 GEMM, R2 structure + T2 XOR swizzle (rule #21:
// linear gload_lds dest + inverse-swizzled global SOURCE + swizzle on READ).
// LDS row stride 128B; byte ^= (row&7)<<4 breaks the 16-way ds_read conflict.
// Best measured configuration (R6: 311.6 us). Do not restructure: 256-tile,
// dbuf, LDS-free, peel, materialization all measured slower (R3-R11).
// MODE 0: per-row exp-sum partials.  MODE 1: write normalized softmax.
template <int MODE>
__global__ __launch_bounds__(256, 3) void gemm_pass(
    const _Float16* __restrict__ A, const _Float16* __restrict__ Bm,
    const float* __restrict__ x2g, const float* __restrict__ w2g,
    const float* __restrict__ invg,
    float* __restrict__ partials,
    float* __restrict__ out) {
  __shared__ _Float16 As[128 * 64];   // 16KB, swizzled contents
  __shared__ _Float16 Bs[128 * 64];   // 16KB
  __shared__ float x2s[128];
  __shared__ float w2s[128];
  __shared__ float invs[128];
  __shared__ float rowpart[2][128];

  // XCD partition: xcd = id&7 owns 16 contiguous col-tiles (w slice 1MB, L2-resident);
  // within an XCD, col-tile varies fastest -> A-tile reused 16x consecutively.
  int id   = blockIdx.x;            // grid = 64 row-tiles * 128 col-tiles = 8192
  int xcd  = id & 7;
  int rest = id >> 3;               // 0..1023
  int ct   = xcd * 16 + (rest & 15);
  int rt   = rest >> 4;             // 0..63
  int brow = rt * 128;
  int bcol = ct * 128;

  int tid = threadIdx.x, lane = tid & 63, wid = tid >> 6;
  int wr = wid >> 1, wc = wid & 1;  // 2x2 waves, each 64x64 output

  if (tid < 128) {
    x2s[tid] = x2g[brow + tid];
    if (MODE == 1) invs[tid] = invg[brow + tid];
  } else {
    w2s[tid - 128] = w2g[bcol + tid - 128];
  }

  vf4 acc[4][4] = {};

  for (int kk = 0; kk < K_DIM; kk += 64) {
    // stage: seg = 8 rows of [row][64] fp16 (1KB). LDS dest linear
    // (base + lane*16); global source column pre-swizzled so that
    // LDS[row][cb] = global[row][cb ^ ((row&7)<<4)]  (involution).
    #pragma unroll
    for (int i = 0; i < 4; ++i) {
      int seg = wid * 4 + i;
      int r   = seg * 8 + (lane >> 3);
      int colhalf = ((lane & 7) * 8) ^ ((lane >> 3) << 3);   // fp16 elems
      gload16(A  + (size_t)(brow + r) * K_DIM + kk + colhalf, (char*)As + seg * 1024);
      gload16(Bm + (size_t)(bcol + r) * K_DIM + kk + colhalf, (char*)Bs + seg * 1024);
    }
    __syncthreads();   // compiler drains vmcnt(0) before s_barrier

    #pragma unroll
    for (int ks = 0; ks < 2; ++ks) {          // two K=32 MFMA steps per BK=64
      half8 af[4], bf[4];
      int cb = ks * 64 + (lane >> 4) * 16;    // column byte within 128B row
      #pragma unroll
      for (int m = 0; m < 4; ++m) {
        int ra = wr * 64 + m * 16 + (lane & 15);
        af[m] = *(const half8*)((const char*)As + ra * 128 + (cb ^ ((ra & 7) << 4)));
      }
      #pragma unroll
      for (int n = 0; n < 4; ++n) {
        int rb = wc * 64 + n * 16 + (lane & 15);
        bf[n] = *(const half8*)((const char*)Bs + rb * 128 + (cb ^ ((rb & 7) << 4)));
      }
      #pragma unroll
      for (int m = 0; m < 4; ++m)
        #pragma unroll
        for (int n = 0; n < 4; ++n)
          acc[m][n] = __builtin_amdgcn_mfma_f32_16x16x32_f16(af[m], bf[n], acc[m][n], 0, 0, 0);
    }
    __syncthreads();
  }

  if (MODE == 0) {
    // epilogue: per-row sums of exp(-2*dist) over this tile's 128 cols
    #pragma unroll
    for (int m = 0; m < 4; ++m) {
      #pragma unroll
      for (int j = 0; j < 4; ++j) {
        int rl = wr * 64 + m * 16 + ((lane >> 4) << 2) + j;   // C/D: row=(lane>>4)*4+j
        float x2v = x2s[rl];
        float sm = 0.f;
        #pragma unroll
        for (int n = 0; n < 4; ++n) {
          int cl = wc * 64 + n * 16 + (lane & 15);            // C/D: col=lane&15
          float d2 = fmaxf(x2v + w2s[cl] - 2.0f * acc[m][n][j], 0.0f);
          sm += __expf(-2.0f * sqrtf(d2));
        }
        // reduce across the 16 lanes (lane&15) sharing this row
        sm += __shfl_xor(sm, 1);
        sm += __shfl_xor(sm, 2);
        sm += __shfl_xor(sm, 4);
        sm += __shfl_xor(sm, 8);
        if ((lane & 15) == 0) rowpart[wc][rl] = sm;
      }
    }
    __syncthreads();
    if (tid < 128)
      partials[(size_t)(brow + tid) * NTILE + ct] = rowpart[0][tid] + rowpart[1][tid];
  } else {
    // epilogue: out = exp(-2*dist) * inv_rowsum
    #pragma unroll
    for (int m = 0; m < 4; ++m) {
      #pragma unroll
      for (int j = 0; j < 4; ++j) {
        int rl = wr * 64 + m * 16 + ((lane >> 4) << 2) + j;
        float x2v = x2s[rl];
        float inv = invs[rl];
        size_t rowbase = (size_t)(brow + rl) * N_COLS + bcol;
        #pragma unroll
        for (int n = 0; n < 4; ++n) {
          int cl = wc * 64 + n * 16 + (lane & 15);
          float d2 = fmaxf(x2v + w2s[cl] - 2.0f * acc[m][n][j], 0.0f);
          out[rowbase + cl] = __expf(-2.0f * sqrtf(d2)) * inv;
        }
      }
    }
  }
}

// ------------- reduce partials -> 1/rowsum, one wave per row -----------
__global__ __launch_bounds__(256) void reduce_inv(
    const float* __restrict__ partials, float* __restrict__ invg) {
  int row  = blockIdx.x * 4 + (threadIdx.x >> 6);
  int lane = threadIdx.x & 63;
  const float* p = partials + (size_t)row * NTILE;
  float s = p[lane] + p[lane + 64];   // NTILE == 128
  #pragma unroll
  for (int off = 32; off > 0; off >>= 1) s += __shfl_down(s, off);
  if (lane == 0) invg[row] = 1.0f / s;
}

// =============== fallback path (ws tiny): logits + row softmax ===============
__global__ __launch_bounds__(256, 2) void gemm_logit_f32(
    const float* __restrict__ xf, const float* __restrict__ wf,
    float* __restrict__ out, int mbase) {
  __shared__ _Float16 As[128 * 64];
  __shared__ _Float16 Bs[128 * 64];
  __shared__ float x2s[128];
  __shared__ float w2s[128];

  int id  = blockIdx.x;
  int xcd = id & 7;
  int rt  = (id >> 3) & 15;
  int c2  = id >> 7;
  int brow = mbase + rt * 128;
  int bcol = (xcd * 16 + c2) * 128;

  int tid = threadIdx.x, lane = tid & 63, wid = tid >> 6;
  int wr = wid >> 1, wc = wid & 1;

  vf4 acc[4][4] = {};

  {
    const float* src = (tid < 128) ? xf + (size_t)(brow + tid) * K_DIM
                                   : wf + (size_t)(bcol + tid - 128) * K_DIM;
    float s = 0.f;
    for (int i = 0; i < 64; ++i) {
      float4 v = ((const float4*)src)[i];
      s += v.x*v.x + v.y*v.y + v.z*v.z + v.w*v.w;
    }
    if (tid < 128) x2s[tid] = s; else w2s[tid - 128] = s;
  }

  for (int kk = 0; kk < K_DIM; kk += 64) {
    #pragma unroll
    for (int i = 0; i < 8; ++i) {
      int idx = i * 256 + tid;
      int r = idx >> 4, kq = idx & 15;
      float4 va = ((const float4*)(xf + (size_t)(brow + r) * K_DIM + kk))[kq];
      float4 vb = ((const float4*)(wf + (size_t)(bcol + r) * K_DIM + kk))[kq];
      half4v ha; ha[0]=(_Float16)va.x; ha[1]=(_Float16)va.y; ha[2]=(_Float16)va.z; ha[3]=(_Float16)va.w;
      half4v hb; hb[0]=(_Float16)vb.x; hb[1]=(_Float16)vb.y; hb[2]=(_Float16)vb.z; hb[3]=(_Float16)vb.w;
      *(half4v*)&As[r * 64 + kq * 4] = ha;
      *(half4v*)&Bs[r * 64 + kq * 4] = hb;
    }
    __syncthreads();
    #pragma unroll
    for (int ks = 0; ks < 2; ++ks) {
      half8 af[4], bf[4];
      #pragma unroll
      for (int m = 0; m < 4; ++m)
        af[m] = *(const half8*)&As[(wr*64 + m*16 + (lane & 15)) * 64 + ks*32 + (lane >> 4) * 8];
      #pragma unroll
      for (int n = 0; n < 4; ++n)
        bf[n] = *(const half8*)&Bs[(wc*64 + n*16 + (lane & 15)) * 64 + ks*32 + (lane >> 4) * 8];
      #pragma unroll
      for (int m = 0; m < 4; ++m)
        #pragma unroll
        for (int n = 0; n < 4; ++n)
          acc[m][n] = __builtin_amdgcn_mfma_f32_16x16x32_f16(af[m], bf[n], acc[m][n], 0, 0, 0);
    }
    __syncthreads();
  }

  #pragma unroll
  for (int m = 0; m < 4; ++m) {
    int rl = wr * 64 + m * 16 + ((lane >> 4) << 2);
    #pragma unroll
    for (int n = 0; n < 4; ++n) {
      int cl = wc * 64 + n * 16 + (lane & 15);
      int c  = bcol + cl;
      float w2v = w2s[cl];
      #pragma unroll
      for (int j = 0; j < 4; ++j) {
        int r = brow + rl + j;
        float d2 = fmaxf(x2s[rl + j] + w2v - 2.0f * acc[m][n][j], 0.0f);
        out[(size_t)r * N_COLS + c] = -2.0f * sqrtf(d2);
      }
    }
  }
}

__global__ __launch_bounds__(256) void softmax_norm(float* __restrict__ io, int mbase) {
  int row = mbase + blockIdx.x;
  float* p = io + (size_t)row * N_COLS;
  int tid = threadIdx.x;
  __shared__ float wsum[4];

  float4 v[16];
  float s = 0.f;
  #pragma unroll
  for (int i = 0; i < 16; ++i) {
    v[i] = ((const float4*)p)[i * 256 + tid];
    v[i].x = __expf(v[i].x); v[i].y = __expf(v[i].y);
    v[i].z = __expf(v[i].z); v[i].w = __expf(v[i].w);
    s += v[i].x + v[i].y + v[i].z + v[i].w;
  }
  #pragma unroll
  for (int off = 32; off > 0; off >>= 1) s += __shfl_down(s, off);
  if ((tid & 63) == 0) wsum[tid >> 6] = s;
  __syncthreads();
  float inv = 1.0f / (wsum[0] + wsum[1] + wsum[2] + wsum[3]);
  #pragma unroll
  for (int i = 0; i < 16; ++i) {
    float4 o = v[i];
    o.x *= inv; o.y *= inv; o.z *= inv; o.w *= inv;
    ((float4*)p)[i * 256 + tid] = o;
  }
}

extern "C" void kernel_launch(void* const* d_in, const int* in_sizes, int n_in,
                              void* d_out, int out_size, void* d_ws, size_t ws_size,
                              hipStream_t stream) {
  const float* x = (const float*)d_in[0];
  const float* w = (const float*)d_in[1];
  float* out = (float*)d_out;

  // ws layout: x2[8192] | w2[16384] | invsum[8192] | partials[8192*128] |
  //            xh fp16 [8192*256] | wh fp16 [16384*256]
  char* ws = (char*)d_ws;
  float* x2 = (float*)ws;
  float* w2 = x2 + M_ROWS;
  float* invsum = w2 + N_COLS;
  float* partials = invsum + M_ROWS;
  _Float16* xh = (_Float16*)(partials + (size_t)M_ROWS * NTILE);
  _Float16* wh = xh + (size_t)M_ROWS * K_DIM;
  const size_t need = ((size_t)(M_ROWS + N_COLS + M_ROWS) + (size_t)M_ROWS * NTILE) * 4
                    + (size_t)(M_ROWS + N_COLS) * K_DIM * 2;

  if (ws_size >= need) {
    prep_kernel<<<(M_ROWS + N_COLS) / 4, 256, 0, stream>>>(x, w, x2, w2, xh, wh);
    gemm_pass<0><<<(M_ROWS / 128) * (N_COLS / 128), 256, 0, stream>>>(
        xh, wh, x2, w2, nullptr, partials, nullptr);
    reduce_inv<<<M_ROWS / 4, 256, 0, stream>>>(partials, invsum);
    gemm_pass<1><<<(M_ROWS / 128) * (N_COLS / 128), 256, 0, stream>>>(
        xh, wh, x2, w2, invsum, nullptr, out);
  } else {
    for (int c = 0; c < NCHUNK; ++c) {
      int mbase = c * CHUNK;
      gemm_logit_f32<<<(CHUNK / 128) * (N_COLS / 128), 256, 0, stream>>>(
          x, w, out, mbase);
      softmax_norm<<<CHUNK, 256, 0, stream>>>(out, mbase);
    }
  }
}